// Round 8
// baseline (361.549 us; speedup 1.0000x reference)
//
#include <hip/hip_runtime.h>

// Problem constants (match reference)
#define BGRAPH 64
#define NNODE  128
#define EMB    16
#define OUTF   64
#define EREAL  65536
#define TOTAL  (BGRAPH * NNODE * NNODE)   // 1048576 pairs
#define EPG    (EREAL / BGRAPH)           // 1024 edges per graph, CONTIGUOUS slice

// Native clang vector type.
typedef float floatx4 __attribute__((ext_vector_type(4)));

#define SLOT_CAP 8
#define CHUNK 256
#define NBLOCKS (TOTAL / CHUNK)   // 4096 blocks, one 256-row chunk each

// ---------------------------------------------------------------------------
// Single fused kernel (round-7 structure, measured 356.8 us total).
// SINGLE CHANGE this round: out_val stores NT -> regular. A/B rationale:
// the harness fill kernel reaches 6.3-6.6 TB/s with regular streaming
// stores; our NT-store kernel runs at 3.8 TB/s effective and writes are 75%
// of its traffic. Round 6's regular-store test was confounded by a
// simultaneous structure change; this isolates the store path.
//
// Per block (chunk = 256 output rows = 2 src nodes of graph g = blockIdx>>6):
//   1. issue gm_val stage loads (16 KB dense)
//   2. issue this graph's edge slice loads (8 KB int4, L2/L3-resident)
//   3. write idx output for this chunk (no load dependence — overlaps latency)
//   4. load W (4 KB, L2 broadcast) into registers
//   5. zero LDS edge-bin counters; ds_write the gm stage; barrier
//   6. scan 1024 edges, LDS-bin the ~16 that land in this chunk
//      (fid>>8 == blockIdx); barrier
//   7. 16-step compute: LDS row broadcast -> 64 FMA -> LDS-binned edge
//      gather -> store (1 KB contiguous per wave-instr)
__global__ __launch_bounds__(256) void fused_kernel(
    const float* __restrict__ gm_val,
    const float* __restrict__ W,
    const int* __restrict__ edge_index,   // [2, EREAL] flat: src then dst
    const float* __restrict__ edge_attr,  // [EREAL, OUTF]
    float* __restrict__ out_val,
    float* __restrict__ out_idx)
{
    __shared__ floatx4  stage[CHUNK * 4];            // 16 KB
    __shared__ unsigned lcnt[CHUNK];                 // 1 KB
    __shared__ unsigned lslot[CHUNK * SLOT_CAP];     // 8 KB

    const int tid  = threadIdx.x;
    const int oq   = tid & 15;                       // lane within group
    const int grp  = tid >> 4;                       // 0..15
    const int base = blockIdx.x * CHUNK;
    const int g    = base >> 14;                     // graph id (= blockIdx>>6)

    // 1) gm stage loads: 4 dense float4 per thread.
    const floatx4* src = (const floatx4*)gm_val + (size_t)base * 4;
    floatx4 s0 = src[tid];
    floatx4 s1 = src[tid + 256];
    floatx4 s2 = src[tid + 512];
    floatx4 s3 = src[tid + 768];

    // 2) edge slice loads: graph g's 1024 src + 1024 dst ints, one int4 each.
    int4 e4s = ((const int4*)(edge_index + g * EPG))[tid];
    int4 e4d = ((const int4*)(edge_index + EREAL + g * EPG))[tid];

    // 3) idx output for this chunk (2 KB, coalesced; independent of loads).
    {
        int p = base + tid;
        out_idx[p]         = (float)(g * NNODE + ((p >> 7) & (NNODE - 1)));
        out_idx[TOTAL + p] = (float)(g * NNODE + (p & (NNODE - 1)));
    }

    // 4) W slice for this lane's output quad (64 floats, L2 broadcast).
    float w[4][16];
    const floatx4* W4 = (const floatx4*)W + oq * 16;
    #pragma unroll
    for (int j = 0; j < 4; ++j) {
        #pragma unroll
        for (int q = 0; q < 4; ++q) {
            floatx4 t = W4[j * 4 + q];
            w[j][q * 4 + 0] = t.x;
            w[j][q * 4 + 1] = t.y;
            w[j][q * 4 + 2] = t.z;
            w[j][q * 4 + 3] = t.w;
        }
    }

    // 5) zero bin counters (tid covers CHUNK exactly) and stage gm chunk.
    lcnt[tid] = 0u;
    stage[tid]       = s0;
    stage[tid + 256] = s1;
    stage[tid + 512] = s2;
    stage[tid + 768] = s3;
    __syncthreads();

    // 6) bin matching edges: fid = src_global*128 + dst_local;
    //    fid>>8 == blockIdx  <=>  fid in [base, base+256).
    #pragma unroll
    for (int i = 0; i < 4; ++i) {
        int es = (i == 0) ? e4s.x : (i == 1) ? e4s.y : (i == 2) ? e4s.z : e4s.w;
        int ed = (i == 0) ? e4d.x : (i == 1) ? e4d.y : (i == 2) ? e4d.z : e4d.w;
        int fid = es * NNODE + (ed & (NNODE - 1));
        if ((fid >> 8) == (int)blockIdx.x) {
            unsigned lr  = (unsigned)(fid & (CHUNK - 1));
            unsigned pos = atomicAdd(&lcnt[lr], 1u);
            if (pos < SLOT_CAP)
                lslot[lr * SLOT_CAP + pos] = (unsigned)(tid * 4 + i); // local id
        }
    }
    __syncthreads();

    // 7) compute: group grp, step s handles local row grp + 16*s. A wave's
    //    4 groups cover 4 consecutive rows -> each store wave-instr writes
    //    1 KB contiguous. Row read from LDS is uniform-address (broadcast).
    for (int s = 0; s < 16; ++s) {
        const int lr = grp + 16 * s;
        const int r  = base + lr;
        const floatx4* rowp = stage + lr * 4;
        floatx4 a = rowp[0], b = rowp[1], c = rowp[2], d = rowp[3];
        float v[16] = {a.x,a.y,a.z,a.w, b.x,b.y,b.z,b.w,
                       c.x,c.y,c.z,c.w, d.x,d.y,d.z,d.w};

        float t0 = 0.f, t1 = 0.f, t2 = 0.f, t3 = 0.f;
        #pragma unroll
        for (int k = 0; k < EMB; ++k) {
            t0 += v[k] * w[0][k];
            t1 += v[k] * w[1][k];
            t2 += v[k] * w[2][k];
            t3 += v[k] * w[3][k];
        }
        floatx4 o = {t0, t1, t2, t3};

        unsigned cR = lcnt[lr];                       // LDS broadcast
        if (cR) {
            unsigned nE = cR < SLOT_CAP ? cR : SLOT_CAP;
            for (unsigned i = 0; i < nE; ++i) {
                unsigned e = (unsigned)(g * EPG) + lslot[lr * SLOT_CAP + i];
                o += *(const floatx4*)(edge_attr + (size_t)e * OUTF + oq * 4);
            }
        }
        // A/B: regular (cached) store — was __builtin_nontemporal_store.
        *(floatx4*)(out_val + (size_t)r * OUTF + oq * 4) = o;
    }
}

extern "C" void kernel_launch(void* const* d_in, const int* in_sizes, int n_in,
                              void* d_out, int out_size, void* d_ws, size_t ws_size,
                              hipStream_t stream)
{
    // inputs (setup_inputs order): batch, edge_index, edge_attr, gm_index, gm_val, W
    const int*   edge_index = (const int*)d_in[1];
    const float* edge_attr  = (const float*)d_in[2];
    const float* gm_val     = (const float*)d_in[4];
    const float* W          = (const float*)d_in[5];

    float* out      = (float*)d_out;
    float* out_idx  = out;                     // first 2*TOTAL elements
    float* out_val  = out + (size_t)2 * TOTAL; // then TOTAL*OUTF elements

    // Single launch: projection + per-block LDS edge binning + gather + idx.
    fused_kernel<<<NBLOCKS, 256, 0, stream>>>(
        gm_val, W, edge_index, edge_attr, out_val, out_idx);
}

// Round 9
// 357.453 us; speedup vs baseline: 1.0115x; 1.0115x over previous
//
#include <hip/hip_runtime.h>

// Problem constants (match reference)
#define BGRAPH 64
#define NNODE  128
#define EMB    16
#define OUTF   64
#define EREAL  65536
#define TOTAL  (BGRAPH * NNODE * NNODE)   // 1048576 pairs
#define EPG    (EREAL / BGRAPH)           // 1024 edges per graph, CONTIGUOUS slice

// Native clang vector type.
typedef float floatx4 __attribute__((ext_vector_type(4)));

#define SLOT_CAP 8
#define CHUNK 256
#define NBLOCKS (TOTAL / CHUNK)   // 4096 blocks, one 256-row chunk each

// ---------------------------------------------------------------------------
// Single fused kernel. Changes vs round-7 measured-best (356.8 us):
//   - NT stores restored (round-8 A/B: regular stores +4.7 us worse).
//   - gm stage now via __builtin_amdgcn_global_load_lds width=16: LDS dest
//     is wave-uniform base + lane*16, which matches our linear stage layout
//     exactly. Removes the 16-VGPR staging round-trip, the vmcnt(0) wait
//     before ds_write, and the ds_writes — DMA fills LDS while the wave
//     proceeds through the edge-scan phase.
//   - lslot u32 -> u16 (local edge id < 4096): LDS 25 KB -> 21 KB.
//
// Per block (chunk = 256 output rows = 2 src nodes of graph g = blockIdx>>6):
//   1. issue gm stage via global_load_lds (4 x 1 KB per wave, async)
//   2. issue this graph's edge slice loads (8 KB int4, L2/L3-resident)
//   3. write idx output for this chunk (overlaps load latency)
//   4. load W (4 KB, L2 broadcast) into registers
//   5. zero LDS bin counters; barrier (also drains the LDS-DMA vmcnt)
//   6. scan 1024 edges, LDS-bin the ~16 that land in this chunk; barrier
//   7. 16-step compute: LDS row broadcast -> 64 FMA -> binned edge gather
//      -> NT store (1 KB contiguous per wave-instr)
__global__ __launch_bounds__(256) void fused_kernel(
    const float* __restrict__ gm_val,
    const float* __restrict__ W,
    const int* __restrict__ edge_index,   // [2, EREAL] flat: src then dst
    const float* __restrict__ edge_attr,  // [EREAL, OUTF]
    float* __restrict__ out_val,
    float* __restrict__ out_idx)
{
    __shared__ floatx4        stage[CHUNK * 4];            // 16 KB
    __shared__ unsigned       lcnt[CHUNK];                 // 1 KB
    __shared__ unsigned short lslot[CHUNK * SLOT_CAP];     // 4 KB

    const int tid  = threadIdx.x;
    const int oq   = tid & 15;                       // lane within group
    const int grp  = tid >> 4;                       // 0..15
    const int base = blockIdx.x * CHUNK;
    const int g    = base >> 14;                     // graph id (= blockIdx>>6)

    // 1) gm stage: async global->LDS DMA, 4 x (1 KB per wave). Linear layout:
    //    thread t's 16 B goes to stage bytes [t*16), source is the same
    //    linear offset in gm_val — exactly the wave-uniform-base + lane*16
    //    pattern global_load_lds writes.
    {
        const float* gsrc = gm_val + (size_t)base * EMB + tid * 4;
        float* ldst = (float*)stage + tid * 4;
        __builtin_amdgcn_global_load_lds(gsrc,        ldst,        16, 0, 0);
        __builtin_amdgcn_global_load_lds(gsrc + 1024, ldst + 1024, 16, 0, 0);
        __builtin_amdgcn_global_load_lds(gsrc + 2048, ldst + 2048, 16, 0, 0);
        __builtin_amdgcn_global_load_lds(gsrc + 3072, ldst + 3072, 16, 0, 0);
    }

    // 2) edge slice loads: graph g's 1024 src + 1024 dst ints, one int4 each.
    int4 e4s = ((const int4*)(edge_index + g * EPG))[tid];
    int4 e4d = ((const int4*)(edge_index + EREAL + g * EPG))[tid];

    // 3) idx output for this chunk (2 KB, coalesced; independent of loads).
    {
        int p = base + tid;
        out_idx[p]         = (float)(g * NNODE + ((p >> 7) & (NNODE - 1)));
        out_idx[TOTAL + p] = (float)(g * NNODE + (p & (NNODE - 1)));
    }

    // 4) W slice for this lane's output quad (64 floats, L2 broadcast).
    float w[4][16];
    const floatx4* W4 = (const floatx4*)W + oq * 16;
    #pragma unroll
    for (int j = 0; j < 4; ++j) {
        #pragma unroll
        for (int q = 0; q < 4; ++q) {
            floatx4 t = W4[j * 4 + q];
            w[j][q * 4 + 0] = t.x;
            w[j][q * 4 + 1] = t.y;
            w[j][q * 4 + 2] = t.z;
            w[j][q * 4 + 3] = t.w;
        }
    }

    // 5) zero bin counters; barrier drains DMA (vmcnt) + orders lcnt.
    lcnt[tid] = 0u;
    __syncthreads();

    // 6) bin matching edges: fid = src_global*128 + dst_local;
    //    fid>>8 == blockIdx  <=>  fid in [base, base+256).
    #pragma unroll
    for (int i = 0; i < 4; ++i) {
        int es = (i == 0) ? e4s.x : (i == 1) ? e4s.y : (i == 2) ? e4s.z : e4s.w;
        int ed = (i == 0) ? e4d.x : (i == 1) ? e4d.y : (i == 2) ? e4d.z : e4d.w;
        int fid = es * NNODE + (ed & (NNODE - 1));
        if ((fid >> 8) == (int)blockIdx.x) {
            unsigned lr  = (unsigned)(fid & (CHUNK - 1));
            unsigned pos = atomicAdd(&lcnt[lr], 1u);
            if (pos < SLOT_CAP)
                lslot[lr * SLOT_CAP + pos] = (unsigned short)(tid * 4 + i);
        }
    }
    __syncthreads();

    // 7) compute: group grp, step s handles local row grp + 16*s. A wave's
    //    4 groups cover 4 consecutive rows -> each NT store wave-instr
    //    writes 1 KB contiguous. LDS row read is uniform-address broadcast.
    for (int s = 0; s < 16; ++s) {
        const int lr = grp + 16 * s;
        const int r  = base + lr;
        const floatx4* rowp = stage + lr * 4;
        floatx4 a = rowp[0], b = rowp[1], c = rowp[2], d = rowp[3];
        float v[16] = {a.x,a.y,a.z,a.w, b.x,b.y,b.z,b.w,
                       c.x,c.y,c.z,c.w, d.x,d.y,d.z,d.w};

        float t0 = 0.f, t1 = 0.f, t2 = 0.f, t3 = 0.f;
        #pragma unroll
        for (int k = 0; k < EMB; ++k) {
            t0 += v[k] * w[0][k];
            t1 += v[k] * w[1][k];
            t2 += v[k] * w[2][k];
            t3 += v[k] * w[3][k];
        }
        floatx4 o = {t0, t1, t2, t3};

        unsigned cR = lcnt[lr];                       // LDS broadcast
        if (cR) {
            unsigned nE = cR < SLOT_CAP ? cR : SLOT_CAP;
            for (unsigned i = 0; i < nE; ++i) {
                unsigned e = (unsigned)(g * EPG) + lslot[lr * SLOT_CAP + i];
                o += *(const floatx4*)(edge_attr + (size_t)e * OUTF + oq * 4);
            }
        }
        __builtin_nontemporal_store(o, (floatx4*)(out_val + (size_t)r * OUTF + oq * 4));
    }
}

extern "C" void kernel_launch(void* const* d_in, const int* in_sizes, int n_in,
                              void* d_out, int out_size, void* d_ws, size_t ws_size,
                              hipStream_t stream)
{
    // inputs (setup_inputs order): batch, edge_index, edge_attr, gm_index, gm_val, W
    const int*   edge_index = (const int*)d_in[1];
    const float* edge_attr  = (const float*)d_in[2];
    const float* gm_val     = (const float*)d_in[4];
    const float* W          = (const float*)d_in[5];

    float* out      = (float*)d_out;
    float* out_idx  = out;                     // first 2*TOTAL elements
    float* out_val  = out + (size_t)2 * TOTAL; // then TOTAL*OUTF elements

    // Single launch: projection + per-block LDS edge binning + gather + idx.
    fused_kernel<<<NBLOCKS, 256, 0, stream>>>(
        gm_val, W, edge_index, edge_attr, out_val, out_idx);
}